// Round 10
// baseline (197.634 us; speedup 1.0000x reference)
//
#include <hip/hip_runtime.h>
#include <hip/hip_bf16.h>

// Problem constants
#define BN_NODES 4096      // B*N = 8*512
#define KNN 16
#define C_POOL 256
#define G_DIM 128
#define IN_DIM 384         // C_POOL + G_DIM
#define L_DIM 512
#define OUT_STRIDE 1920    // 384 + 3*512

#define X1_OFF 384
#define X2_OFF 896
#define X3_OFF 1408

typedef __attribute__((ext_vector_type(8))) __bf16 bf16x8;
typedef __attribute__((ext_vector_type(4))) float floatx4;

static __device__ __forceinline__ ushort f2bf(float v) {
  return __builtin_bit_cast(ushort, __float2bfloat16(v));
}
static __device__ __forceinline__ float bf2f(ushort u) {
  return __builtin_bit_cast(float, ((unsigned)u) << 16);
}

// ---------------------------------------------------------------------------
// Kernel 1 (prep): blocks [0,512): node_feat (8 nodes/block);
//                  blocks [512,1920): wconv for all 3 layers.  (R6 verbatim)
// ---------------------------------------------------------------------------
__global__ __launch_bounds__(256) void prep_kernel(
    const float* __restrict__ rois, const float* __restrict__ pooled,
    const float* __restrict__ gW1, const float* __restrict__ gb1,
    const float* __restrict__ gW2, const float* __restrict__ gb2,
    const float* __restrict__ W0, const float* __restrict__ W1,
    const float* __restrict__ W2, float* __restrict__ out,
    ushort* __restrict__ Xb0, ushort* __restrict__ Wb0,
    ushort* __restrict__ Wb1, ushort* __restrict__ Wb2) {
  const int t = threadIdx.x;
  if (blockIdx.x >= 512) {
    int wi = blockIdx.x - 512;
    const float* W;
    ushort* Wb;
    int K, base;
    if (wi < 384) {
      W = W0; Wb = Wb0; K = IN_DIM; base = wi;
    } else if (wi < 896) {
      W = W1; Wb = Wb1; K = L_DIM; base = wi - 384;
    } else {
      W = W2; Wb = Wb2; K = L_DIM; base = wi - 896;
    }
    int elem = base * 1024 + t * 4;
    int j = elem / K;
    int k = elem - j * K;
    const float* srcp = (j < 512) ? W + (size_t)j * (2 * K) + k
                                  : W + (size_t)(j - 512) * (2 * K) + K + k;
    ushort4 pk;
    pk.x = f2bf(srcp[0]);
    pk.y = f2bf(srcp[1]);
    pk.z = f2bf(srcp[2]);
    pk.w = f2bf(srcp[3]);
    *(ushort4*)(Wb + (size_t)j * K + k) = pk;
    return;
  }
  const int nb = blockIdx.x * 8;
  const int c = t & 127;
  const int nh = t >> 7;
  __shared__ float rs[8 * 7];
  __shared__ __align__(16) float h1[8][G_DIM];
  if (t < 56) rs[t] = rois[(size_t)nb * 7 + t];
  __syncthreads();
  {
    float w1[7];
#pragma unroll
    for (int i = 0; i < 7; i++) w1[i] = gW1[c * 7 + i];
    float b1 = gb1[c];
#pragma unroll
    for (int n = nh * 4; n < nh * 4 + 4; n++) {
      float a = b1;
#pragma unroll
      for (int i = 0; i < 7; i++) a += rs[n * 7 + i] * w1[i];
      h1[n][c] = fmaxf(a, 0.f);
    }
  }
  __syncthreads();
  float acc[4];
  {
    float b2 = gb2[c];
#pragma unroll
    for (int n = 0; n < 4; n++) acc[n] = b2;
    const float4* w4 = (const float4*)(gW2 + (size_t)c * G_DIM);
#pragma unroll 4
    for (int kc = 0; kc < G_DIM / 4; kc++) {
      float4 wv = w4[kc];
#pragma unroll
      for (int n = 0; n < 4; n++) {
        float4 hv = ((const float4*)h1[nh * 4 + n])[kc];
        acc[n] += wv.x * hv.x + wv.y * hv.y + wv.z * hv.z + wv.w * hv.w;
      }
    }
  }
#pragma unroll
  for (int n = 0; n < 4; n++) {
    int node = nb + nh * 4 + n;
    float g = fmaxf(acc[n], 0.f);
    const float* prow = pooled + (size_t)node * C_POOL;
    float p0 = prow[c], p1 = prow[G_DIM + c];
    float* orow = out + (size_t)node * OUT_STRIDE;
    orow[c] = p0;
    orow[G_DIM + c] = p1;
    orow[C_POOL + c] = g;
    ushort* xrow = Xb0 + (size_t)node * IN_DIM;
    xrow[c] = f2bf(p0);
    xrow[G_DIM + c] = f2bf(p1);
    xrow[C_POOL + c] = f2bf(g);
  }
}

// ---------------------------------------------------------------------------
// Kernel 2: fused layer, REGISTER-DIRECT GEMM (no LDS staging, no K-loop
// barriers). Block = (stripe s 0..31, batch b 0..7) = 256 blocks x 1024 thr
// = 16 waves (4/SIMD). Wave w owns rows [w*32, w*32+32) of the batch's 512
// nodes; computes 2x2 16x16 tiles vs the stripe's 32 B-rows (16 P + 16 Q).
// MFMA A/B fragments are loaded straight from global into VGPRs:
//   lane l -> row fr=l&15, k-chunk kc=l>>4 (8 bf16 = 16 B = one dwordx4).
// Compiler software-pipelines the unrolled K-loop (vmcnt(N) on reg deps) --
// the fine-grained overlap the global_load_lds+barrier structure can't do.
// Epilogue: acc -> sPQ[node][32ch] (stride 36: 2-way bank alias = free),
// ONE __syncthreads, then in-LDS edge max+relu.
// ---------------------------------------------------------------------------
__global__ __launch_bounds__(1024) void layer_kernel(
    const ushort* __restrict__ Xin, int ldx, int K,
    const ushort* __restrict__ Wb, const int* __restrict__ src,
    const float* __restrict__ bias, float* __restrict__ out, int out_off,
    ushort* __restrict__ Xout, int write_x) {
  __shared__ __align__(16) ushort sPQ[512 * 36];  // 36 KB
  const int s = blockIdx.x;
  const int b = blockIdx.y;
  const int tid = threadIdx.x;
  const int lane = tid & 63;
  const int w = tid >> 6;        // wave 0..15
  const int fr = lane & 15;
  const int kc = lane >> 4;

  // per-lane fragment base pointers (16 B loads at +kt*32 elems)
  const ushort* A0 = Xin + (size_t)(b * 512 + w * 32 + fr) * ldx + kc * 8;
  const ushort* A1 = A0 + (size_t)16 * ldx;
  const ushort* B0 = Wb + (size_t)(s * 16 + fr) * K + kc * 8;
  const ushort* B1 = Wb + (size_t)(512 + s * 16 + fr) * K + kc * 8;

  floatx4 acc[2][2];
#pragma unroll
  for (int i = 0; i < 2; i++)
#pragma unroll
    for (int j = 0; j < 2; j++) acc[i][j] = (floatx4){0.f, 0.f, 0.f, 0.f};

  const int nkt = K >> 5;  // 12 or 16
#pragma unroll 4
  for (int kt = 0; kt < nkt; kt++) {
    bf16x8 a0 = *(const bf16x8*)(A0 + kt * 32);
    bf16x8 a1 = *(const bf16x8*)(A1 + kt * 32);
    bf16x8 b0 = *(const bf16x8*)(B0 + kt * 32);
    bf16x8 b1 = *(const bf16x8*)(B1 + kt * 32);
    acc[0][0] = __builtin_amdgcn_mfma_f32_16x16x32_bf16(a0, b0, acc[0][0], 0, 0, 0);
    acc[0][1] = __builtin_amdgcn_mfma_f32_16x16x32_bf16(a0, b1, acc[0][1], 0, 0, 0);
    acc[1][0] = __builtin_amdgcn_mfma_f32_16x16x32_bf16(a1, b0, acc[1][0], 0, 0, 0);
    acc[1][1] = __builtin_amdgcn_mfma_f32_16x16x32_bf16(a1, b1, acc[1][1], 0, 0, 0);
  }

  // epilogue: C/D layout col=fr, row=kc*4+reg (m89-verified); row stride 36
#pragma unroll
  for (int i = 0; i < 2; i++)
#pragma unroll
    for (int ct = 0; ct < 2; ct++)
#pragma unroll
      for (int r = 0; r < 4; r++)
        sPQ[(w * 32 + i * 16 + kc * 4 + r) * 36 + ct * 16 + fr] =
            f2bf(acc[i][ct][r]);
  __syncthreads();

  // ---- edge phase: thread = (node n = tid>>1, 8-ch half h = tid&1) ----
  {
    const int n = tid >> 1;
    const int h = tid & 1;
    const int* sp = src + (size_t)(b * 512 + n) * KNN;
    int nbr[KNN];
#pragma unroll
    for (int k4 = 0; k4 < 4; k4++) {
      int4 v = ((const int4*)sp)[k4];
      nbr[k4 * 4 + 0] = v.x - b * 512;
      nbr[k4 * 4 + 1] = v.y - b * 512;
      nbr[k4 * 4 + 2] = v.z - b * 512;
      nbr[k4 * 4 + 3] = v.w - b * 512;
    }
    float m[8];
#pragma unroll
    for (int c = 0; c < 8; c++) m[c] = -1e30f;
#pragma unroll
    for (int k = 0; k < KNN; k++) {
      const ushort* pr = &sPQ[nbr[k] * 36 + h * 8];
      ushort4 u0 = *(const ushort4*)pr;
      ushort4 u1 = *(const ushort4*)(pr + 4);
      m[0] = fmaxf(m[0], bf2f(u0.x));
      m[1] = fmaxf(m[1], bf2f(u0.y));
      m[2] = fmaxf(m[2], bf2f(u0.z));
      m[3] = fmaxf(m[3], bf2f(u0.w));
      m[4] = fmaxf(m[4], bf2f(u1.x));
      m[5] = fmaxf(m[5], bf2f(u1.y));
      m[6] = fmaxf(m[6], bf2f(u1.z));
      m[7] = fmaxf(m[7], bf2f(u1.w));
    }
    const ushort* own = &sPQ[n * 36 + h * 8];
    float res[8];
#pragma unroll
    for (int c = 0; c < 8; c++) {
      float p = bf2f(own[c]);
      float q = bf2f(own[16 + c]);
      float bb = bias[s * 16 + h * 8 + c];
      res[c] = fmaxf(m[c] - p + q + bb, 0.f);
    }
    float* orow = out + (size_t)(b * 512 + n) * OUT_STRIDE + out_off + s * 16 +
                  h * 8;
    *(float4*)orow = (float4){res[0], res[1], res[2], res[3]};
    *(float4*)(orow + 4) = (float4){res[4], res[5], res[6], res[7]};
    if (write_x) {
      ushort* xrow = Xout + (size_t)(b * 512 + n) * L_DIM + s * 16 + h * 8;
      ushort4 p0, p1;
      p0.x = f2bf(res[0]); p0.y = f2bf(res[1]);
      p0.z = f2bf(res[2]); p0.w = f2bf(res[3]);
      p1.x = f2bf(res[4]); p1.y = f2bf(res[5]);
      p1.z = f2bf(res[6]); p1.w = f2bf(res[7]);
      *(ushort4*)xrow = p0;
      *(ushort4*)(xrow + 4) = p1;
    }
  }
}

extern "C" void kernel_launch(void* const* d_in, const int* in_sizes, int n_in,
                              void* d_out, int out_size, void* d_ws,
                              size_t ws_size, hipStream_t stream) {
  const float* rois = (const float*)d_in[0];
  const float* pooled = (const float*)d_in[1];
  const int* edge_index = (const int*)d_in[2];
  const float* gW1 = (const float*)d_in[3];
  const float* gb1 = (const float*)d_in[4];
  const float* gW2 = (const float*)d_in[5];
  const float* gb2 = (const float*)d_in[6];
  const float* fcW[3] = {(const float*)d_in[7], (const float*)d_in[9],
                         (const float*)d_in[11]};
  const float* fcb[3] = {(const float*)d_in[8], (const float*)d_in[10],
                         (const float*)d_in[12]};
  float* out = (float*)d_out;
  const int* src = edge_index;  // dst[e] == e/16 by construction

  // workspace layout (bytes):
  //   Xb0 : 4096*384 bf16 = 3 MB   @ 0
  //   Xb1 : 4096*512 bf16 = 4 MB   @ 4 MB
  //   Xb2 : 4096*512 bf16 = 4 MB   @ 8 MB
  //   Wb0 : 1024*384 bf16          @ 12 MB
  //   Wb1 : 1024*512 bf16          @ 13 MB
  //   Wb2 : 1024*512 bf16          @ 14 MB
  char* ws = (char*)d_ws;
  ushort* Xb0 = (ushort*)ws;
  ushort* Xb1 = (ushort*)(ws + (size_t)4 * 1024 * 1024);
  ushort* Xb2 = (ushort*)(ws + (size_t)8 * 1024 * 1024);
  ushort* Wb0 = (ushort*)(ws + (size_t)12 * 1024 * 1024);
  ushort* Wb1 = (ushort*)(ws + (size_t)13 * 1024 * 1024);
  ushort* Wb2 = (ushort*)(ws + (size_t)14 * 1024 * 1024);

  prep_kernel<<<1920, 256, 0, stream>>>(rois, pooled, gW1, gb1, gW2, gb2,
                                        fcW[0], fcW[1], fcW[2], out, Xb0, Wb0,
                                        Wb1, Wb2);
  layer_kernel<<<dim3(32, 8), 1024, 0, stream>>>(Xb0, IN_DIM, IN_DIM, Wb0, src,
                                                 fcb[0], out, X1_OFF, Xb1, 1);
  layer_kernel<<<dim3(32, 8), 1024, 0, stream>>>(Xb1, L_DIM, L_DIM, Wb1, src,
                                                 fcb[1], out, X2_OFF, Xb2, 1);
  layer_kernel<<<dim3(32, 8), 1024, 0, stream>>>(Xb2, L_DIM, L_DIM, Wb2, src,
                                                 fcb[2], out, X3_OFF, Xb2, 0);
}

// Round 11
// 169.653 us; speedup vs baseline: 1.1649x; 1.1649x over previous
//
#include <hip/hip_runtime.h>
#include <hip/hip_bf16.h>

// Problem constants
#define BN_NODES 4096      // B*N = 8*512
#define KNN 16
#define C_POOL 256
#define G_DIM 128
#define IN_DIM 384         // C_POOL + G_DIM
#define L_DIM 512
#define OUT_STRIDE 1920    // 384 + 3*512

#define X1_OFF 384
#define X2_OFF 896
#define X3_OFF 1408

typedef __attribute__((ext_vector_type(8))) __bf16 bf16x8;
typedef __attribute__((ext_vector_type(4))) float floatx4;
typedef __attribute__((ext_vector_type(8))) unsigned short ushortx8;

static __device__ __forceinline__ ushort f2bf(float v) {
  return __builtin_bit_cast(ushort, __float2bfloat16(v));
}
static __device__ __forceinline__ float bf2f(ushort u) {
  return __builtin_bit_cast(float, ((unsigned)u) << 16);
}
static __device__ __forceinline__ void gld_lds(const ushort* g, ushort* l) {
  __builtin_amdgcn_global_load_lds(
      (const __attribute__((address_space(1))) void*)g,
      (__attribute__((address_space(3))) void*)l, 16, 0, 0);
}

// ---------------------------------------------------------------------------
// Kernel 1 (prep): blocks [0,512): node_feat (8 nodes/block);
//                  blocks [512,1920): wconv for all 3 layers.  (R6 verbatim)
// ---------------------------------------------------------------------------
__global__ __launch_bounds__(256) void prep_kernel(
    const float* __restrict__ rois, const float* __restrict__ pooled,
    const float* __restrict__ gW1, const float* __restrict__ gb1,
    const float* __restrict__ gW2, const float* __restrict__ gb2,
    const float* __restrict__ W0, const float* __restrict__ W1,
    const float* __restrict__ W2, float* __restrict__ out,
    ushort* __restrict__ Xb0, ushort* __restrict__ Wb0,
    ushort* __restrict__ Wb1, ushort* __restrict__ Wb2) {
  const int t = threadIdx.x;
  if (blockIdx.x >= 512) {
    int wi = blockIdx.x - 512;
    const float* W;
    ushort* Wb;
    int K, base;
    if (wi < 384) {
      W = W0; Wb = Wb0; K = IN_DIM; base = wi;
    } else if (wi < 896) {
      W = W1; Wb = Wb1; K = L_DIM; base = wi - 384;
    } else {
      W = W2; Wb = Wb2; K = L_DIM; base = wi - 896;
    }
    int elem = base * 1024 + t * 4;
    int j = elem / K;
    int k = elem - j * K;
    const float* srcp = (j < 512) ? W + (size_t)j * (2 * K) + k
                                  : W + (size_t)(j - 512) * (2 * K) + K + k;
    ushort4 pk;
    pk.x = f2bf(srcp[0]);
    pk.y = f2bf(srcp[1]);
    pk.z = f2bf(srcp[2]);
    pk.w = f2bf(srcp[3]);
    *(ushort4*)(Wb + (size_t)j * K + k) = pk;
    return;
  }
  const int nb = blockIdx.x * 8;
  const int c = t & 127;
  const int nh = t >> 7;
  __shared__ float rs[8 * 7];
  __shared__ __align__(16) float h1[8][G_DIM];
  if (t < 56) rs[t] = rois[(size_t)nb * 7 + t];
  __syncthreads();
  {
    float w1[7];
#pragma unroll
    for (int i = 0; i < 7; i++) w1[i] = gW1[c * 7 + i];
    float b1 = gb1[c];
#pragma unroll
    for (int n = nh * 4; n < nh * 4 + 4; n++) {
      float a = b1;
#pragma unroll
      for (int i = 0; i < 7; i++) a += rs[n * 7 + i] * w1[i];
      h1[n][c] = fmaxf(a, 0.f);
    }
  }
  __syncthreads();
  float acc[4];
  {
    float b2 = gb2[c];
#pragma unroll
    for (int n = 0; n < 4; n++) acc[n] = b2;
    const float4* w4 = (const float4*)(gW2 + (size_t)c * G_DIM);
#pragma unroll 4
    for (int kc = 0; kc < G_DIM / 4; kc++) {
      float4 wv = w4[kc];
#pragma unroll
      for (int n = 0; n < 4; n++) {
        float4 hv = ((const float4*)h1[nh * 4 + n])[kc];
        acc[n] += wv.x * hv.x + wv.y * hv.y + wv.z * hv.z + wv.w * hv.w;
      }
    }
  }
#pragma unroll
  for (int n = 0; n < 4; n++) {
    int node = nb + nh * 4 + n;
    float g = fmaxf(acc[n], 0.f);
    const float* prow = pooled + (size_t)node * C_POOL;
    float p0 = prow[c], p1 = prow[G_DIM + c];
    float* orow = out + (size_t)node * OUT_STRIDE;
    orow[c] = p0;
    orow[G_DIM + c] = p1;
    orow[C_POOL + c] = g;
    ushort* xrow = Xb0 + (size_t)node * IN_DIM;
    xrow[c] = f2bf(p0);
    xrow[G_DIM + c] = f2bf(p1);
    xrow[C_POOL + c] = f2bf(g);
  }
}

// ---------------------------------------------------------------------------
// Kernel 2: bf16 MFMA GEMM (R6 champion shape, K templated for full unroll).
// PQb[4096 x 1024] = Xb[4096 x K] @ Wb[1024 x K]^T.
// Tile 128x64, BK=64, 512 threads = 8 waves (4x2), wave = 32x32 (2x2 tiles).
// grid (32,16) = 512 blocks = 2 blocks/CU, 16 waves/CU.
// LDS in MFMA fragment order: 16x32 tile = 64 lane-fragments contiguous
// (1 KB/tile); frag ds_read_b128 at tile_base + lane*16 -> conflict-free.
// ---------------------------------------------------------------------------
template <int K>
__global__ __launch_bounds__(512) void mfma_gemm_kernel(
    const ushort* __restrict__ Xb, const ushort* __restrict__ Wb,
    ushort* __restrict__ PQb) {
  __shared__ ushort sA[128 * 64];  // 16 KB, 16 tiles
  __shared__ ushort sB[64 * 64];   // 8 KB, 8 tiles
  const int tid = threadIdx.x;
  const int lane = tid & 63;
  const int w = tid >> 6;          // wave 0..7
  const int wm = w >> 1;           // 0..3 (32-row band)
  const int wn = w & 1;            // 0..1 (32-col band)
  const int fr = lane & 15;
  const int kc = lane >> 4;
  const int bm = blockIdx.x, bn = blockIdx.y;

  floatx4 acc[2][2];
#pragma unroll
  for (int i = 0; i < 2; i++)
#pragma unroll
    for (int j = 0; j < 2; j++) acc[i][j] = (floatx4){0.f, 0.f, 0.f, 0.f};

#pragma unroll
  for (int k0 = 0; k0 < K; k0 += 64) {
#pragma unroll
    for (int r = 0; r < 2; r++) {
      int ta = w + r * 8;          // wave-uniform
      int rt = ta >> 1, ks = ta & 1;
      const ushort* ga =
          Xb + (size_t)(bm * 128 + rt * 16 + fr) * K + k0 + ks * 32 + kc * 8;
      gld_lds(ga, &sA[ta * 512 + lane * 8]);
    }
    {
      int ct = w >> 1, ks = w & 1;
      const ushort* gb =
          Wb + (size_t)(bn * 64 + ct * 16 + fr) * K + k0 + ks * 32 + kc * 8;
      gld_lds(gb, &sB[w * 512 + lane * 8]);
    }
    __syncthreads();
#pragma unroll
    for (int ks = 0; ks < 2; ks++) {
      bf16x8 af[2], bf[2];
#pragma unroll
      for (int i = 0; i < 2; i++)
        af[i] = *(const bf16x8*)&sA[((wm * 2 + i) * 2 + ks) * 512 + lane * 8];
#pragma unroll
      for (int j = 0; j < 2; j++)
        bf[j] = *(const bf16x8*)&sB[((wn * 2 + j) * 2 + ks) * 512 + lane * 8];
#pragma unroll
      for (int i = 0; i < 2; i++)
#pragma unroll
        for (int j = 0; j < 2; j++)
          acc[i][j] = __builtin_amdgcn_mfma_f32_16x16x32_bf16(af[i], bf[j],
                                                              acc[i][j], 0, 0,
                                                              0);
    }
    __syncthreads();
  }

  // C/D layout: col = fr, row = kc*4 + reg (m89-verified)
  const int rowB = bm * 128 + wm * 32 + kc * 4;
  const int colB = bn * 64 + wn * 32 + fr;
#pragma unroll
  for (int i = 0; i < 2; i++)
#pragma unroll
    for (int j = 0; j < 2; j++)
#pragma unroll
      for (int r = 0; r < 4; r++)
        PQb[(size_t)(rowB + i * 16 + r) * 1024 + colB + j * 16] =
            f2bf(acc[i][j][r]);
}

// ---------------------------------------------------------------------------
// Kernel 3: edge gather + max + relu. One WAVE per node; lane = 8 channels
// (16 B). Neighbor row read = one fully coalesced 1 KB wave load; 17
// independent loads in flight. grid 512 blocks x 512 threads (8 nodes/blk).
// ---------------------------------------------------------------------------
__global__ __launch_bounds__(512) void edge_kernel(
    const ushort* __restrict__ PQb, const int* __restrict__ src,
    const float* __restrict__ bias, float* __restrict__ out, int out_off,
    ushort* __restrict__ Xb, int write_x) {
  const int n = blockIdx.x * 8 + (threadIdx.x >> 6);
  const int l = threadIdx.x & 63;

  int nbr[KNN];
  {
    const int4* sp = (const int4*)(src + (size_t)n * KNN);
#pragma unroll
    for (int k4 = 0; k4 < 4; k4++) {
      int4 v = sp[k4];  // same addr across wave -> broadcast
      nbr[k4 * 4 + 0] = v.x;
      nbr[k4 * 4 + 1] = v.y;
      nbr[k4 * 4 + 2] = v.z;
      nbr[k4 * 4 + 3] = v.w;
    }
  }

  const ushort* own = PQb + (size_t)n * 1024 + l * 8;
  ushortx8 pu = *(const ushortx8*)own;
  ushortx8 qu = *(const ushortx8*)(own + 512);

  float m[8];
#pragma unroll
  for (int c = 0; c < 8; c++) m[c] = -1e30f;
#pragma unroll
  for (int k = 0; k < KNN; k++) {
    ushortx8 u = *(const ushortx8*)(PQb + (size_t)nbr[k] * 1024 + l * 8);
#pragma unroll
    for (int c = 0; c < 8; c++) m[c] = fmaxf(m[c], bf2f(u[c]));
  }

  const float4 bb0 = *(const float4*)&bias[l * 8];
  const float4 bb1 = *(const float4*)&bias[l * 8 + 4];
  float res[8];
#pragma unroll
  for (int c = 0; c < 8; c++) {
    float bbv = (c < 4) ? ((const float*)&bb0)[c] : ((const float*)&bb1)[c - 4];
    res[c] = fmaxf(m[c] - bf2f(pu[c]) + bf2f(qu[c]) + bbv, 0.f);
  }

  float* orow = out + (size_t)n * OUT_STRIDE + out_off + l * 8;
  *(float4*)orow = (float4){res[0], res[1], res[2], res[3]};
  *(float4*)(orow + 4) = (float4){res[4], res[5], res[6], res[7]};
  if (write_x) {
    ushortx8 pk;
#pragma unroll
    for (int c = 0; c < 8; c++) pk[c] = f2bf(res[c]);
    *(ushortx8*)(Xb + (size_t)n * L_DIM + l * 8) = pk;
  }
}

extern "C" void kernel_launch(void* const* d_in, const int* in_sizes, int n_in,
                              void* d_out, int out_size, void* d_ws,
                              size_t ws_size, hipStream_t stream) {
  const float* rois = (const float*)d_in[0];
  const float* pooled = (const float*)d_in[1];
  const int* edge_index = (const int*)d_in[2];
  const float* gW1 = (const float*)d_in[3];
  const float* gb1 = (const float*)d_in[4];
  const float* gW2 = (const float*)d_in[5];
  const float* gb2 = (const float*)d_in[6];
  const float* fcW[3] = {(const float*)d_in[7], (const float*)d_in[9],
                         (const float*)d_in[11]};
  const float* fcb[3] = {(const float*)d_in[8], (const float*)d_in[10],
                         (const float*)d_in[12]};
  float* out = (float*)d_out;
  const int* src = edge_index;  // dst[e] == e/16 by construction

  // workspace layout (bytes):
  //   PQb : 4096*1024 bf16 = 8 MB  @ 0
  //   Xb  : 4096*512  bf16 = 4 MB  @ 8 MB  (stride IN_DIM for x0, L_DIM after)
  //   Wb0 : 1024*384  bf16         @ 12 MB
  //   Wb1 : 1024*512  bf16         @ 13 MB
  //   Wb2 : 1024*512  bf16         @ 14 MB
  char* ws = (char*)d_ws;
  ushort* PQb = (ushort*)ws;
  ushort* Xb = (ushort*)(ws + (size_t)8 * 1024 * 1024);
  ushort* Wb[3] = {(ushort*)(ws + (size_t)12 * 1024 * 1024),
                   (ushort*)(ws + (size_t)13 * 1024 * 1024),
                   (ushort*)(ws + (size_t)14 * 1024 * 1024)};

  prep_kernel<<<1920, 256, 0, stream>>>(rois, pooled, gW1, gb1, gW2, gb2,
                                        fcW[0], fcW[1], fcW[2], out, Xb, Wb[0],
                                        Wb[1], Wb[2]);

  mfma_gemm_kernel<IN_DIM><<<dim3(32, 16), 512, 0, stream>>>(Xb, Wb[0], PQb);
  edge_kernel<<<512, 512, 0, stream>>>(PQb, src, fcb[0], out, X1_OFF, Xb, 1);
  mfma_gemm_kernel<L_DIM><<<dim3(32, 16), 512, 0, stream>>>(Xb, Wb[1], PQb);
  edge_kernel<<<512, 512, 0, stream>>>(PQb, src, fcb[1], out, X2_OFF, Xb, 1);
  mfma_gemm_kernel<L_DIM><<<dim3(32, 16), 512, 0, stream>>>(Xb, Wb[2], PQb);
  edge_kernel<<<512, 512, 0, stream>>>(PQb, src, fcb[2], out, X3_OFF, Xb, 0);
}